// Round 1
// baseline (9398.459 us; speedup 1.0000x reference)
//
#include <hip/hip_runtime.h>

// ScannedRNN (flax GRUCell with per-step carry reset), T=512, B=128, H=512.
// Strategy R0: gi = X@Wi+bi hoisted to one big f16-MFMA GEMM; recurrence done
// as 512 small per-step kernels (h ping-pongs through global). f16 everywhere
// for MFMA inputs, fp32 accum + fp32 master h for the z*h term.

typedef _Float16 f16;
typedef _Float16 f16x8 __attribute__((ext_vector_type(8)));
typedef float f32x4 __attribute__((ext_vector_type(4)));

#define TT 512
#define BB 128
#define HH 512
#define H3 1536
#define TBR 65536  // TT*BB rows

// ---------------------------------------------------------------- k_prep ----
// WiT/WhT: [3H][H] f16 transposed copies so MFMA B-fragments read 8 contiguous
// k per lane (ds_read_b128). Also init ping-pong h buffers from h0.
__global__ __launch_bounds__(256) void k_prep(
    const float* __restrict__ Wi, const float* __restrict__ Wh,
    const float* __restrict__ h0,
    f16* __restrict__ WiT, f16* __restrict__ WhT,
    float* __restrict__ h32, f16* __restrict__ h16) {
  int idx = blockIdx.x * 256 + threadIdx.x;
  if (idx < HH * H3) {
    int n = idx >> 9;         // 0..1535 (output col)
    int k = idx & (HH - 1);   // 0..511
    WiT[idx] = (f16)Wi[(size_t)k * H3 + n];
    WhT[idx] = (f16)Wh[(size_t)k * H3 + n];
  }
  if (idx < BB * HH) {
    float v = h0[idx];
    h32[idx] = v;
    h16[idx] = (f16)v;
  }
}

// ------------------------------------------------------------- k_gemm_gi ----
// gi[i,j] = sum_k x[i,k]*Wi[k,j] + bi[j]; i in [0,65536), j in [0,1536).
// 64x64 block tile, 4 waves in 2x2 of 32x32, K-step 32, f16 MFMA 16x16x32.
__global__ __launch_bounds__(256) void k_gemm_gi(
    const float* __restrict__ x, const f16* __restrict__ WiT,
    const float* __restrict__ bi, f16* __restrict__ gi) {
  __shared__ f16 As[64 * 48];  // [row][k] stride 48 halfs (16B aligned rows)
  __shared__ f16 Bs[64 * 48];  // [col][k]
  const int tid = threadIdx.x;
  const int lane = tid & 63;
  const int w = tid >> 6;
  const int i0 = blockIdx.x * 64;
  const int j0 = blockIdx.y * 64;
  const int mw = (w & 1) * 32;   // wave m offset
  const int nw = (w >> 1) * 32;  // wave n offset

  f32x4 acc[2][2] = {};

  const int srow = tid >> 2;       // 0..63
  const int skp = (tid & 3) * 8;   // 0,8,16,24

  const int fr = lane & 15;
  const int fq8 = (lane >> 4) * 8;

  for (int kb = 0; kb < 16; ++kb) {
    const int k0 = kb * 32;
    // stage A: x f32 -> f16
    const float* xp = x + (size_t)(i0 + srow) * HH + k0 + skp;
    float4 v0 = *(const float4*)xp;
    float4 v1 = *(const float4*)(xp + 4);
    f16x8 a8;
    a8[0] = (f16)v0.x; a8[1] = (f16)v0.y; a8[2] = (f16)v0.z; a8[3] = (f16)v0.w;
    a8[4] = (f16)v1.x; a8[5] = (f16)v1.y; a8[6] = (f16)v1.z; a8[7] = (f16)v1.w;
    *(f16x8*)&As[srow * 48 + skp] = a8;
    // stage B: WiT f16 copy (row-major [n][k], contiguous)
    *(f16x8*)&Bs[srow * 48 + skp] =
        *(const f16x8*)(WiT + (size_t)(j0 + srow) * HH + k0 + skp);
    __syncthreads();
    f16x8 af0 = *(const f16x8*)&As[(mw + fr) * 48 + fq8];
    f16x8 af1 = *(const f16x8*)&As[(mw + 16 + fr) * 48 + fq8];
    f16x8 bf0 = *(const f16x8*)&Bs[(nw + fr) * 48 + fq8];
    f16x8 bf1 = *(const f16x8*)&Bs[(nw + 16 + fr) * 48 + fq8];
    acc[0][0] = __builtin_amdgcn_mfma_f32_16x16x32_f16(af0, bf0, acc[0][0], 0, 0, 0);
    acc[0][1] = __builtin_amdgcn_mfma_f32_16x16x32_f16(af0, bf1, acc[0][1], 0, 0, 0);
    acc[1][0] = __builtin_amdgcn_mfma_f32_16x16x32_f16(af1, bf0, acc[1][0], 0, 0, 0);
    acc[1][1] = __builtin_amdgcn_mfma_f32_16x16x32_f16(af1, bf1, acc[1][1], 0, 0, 0);
    __syncthreads();
  }
  // epilogue: C/D layout col=lane&15, row=(lane>>4)*4+reg
  const int trow = (lane >> 4) * 4;
  for (int mi = 0; mi < 2; ++mi)
    for (int ni = 0; ni < 2; ++ni)
      for (int r = 0; r < 4; ++r) {
        int row = mw + mi * 16 + trow + r;
        int col = nw + ni * 16 + fr;
        int j = j0 + col;
        gi[(size_t)(i0 + row) * H3 + j] = (f16)(acc[mi][ni][r] + bi[j]);
      }
}

// ---------------------------------------------------------------- k_step ----
// One GRU step for tile [32 b-rows x 64 j-cols]. Computes gh for the 3 gate
// column groups (j, j+H, j+2H) with f16 MFMA, then fused gate math + h update.
// h state ping-pongs via global (h32 fp32 master, h16 f16 MFMA mirror).
__global__ __launch_bounds__(256) void k_step(
    int t, const int* __restrict__ resets, const f16* __restrict__ WhT,
    const f16* __restrict__ gi, const float* __restrict__ bhn,
    float* __restrict__ out,
    const float* __restrict__ h32i, float* __restrict__ h32o,
    const f16* __restrict__ h16i, f16* __restrict__ h16o) {
  __shared__ f16 As[32 * 520];  // full [32 rows][512 k] h tile, stride 520
  __shared__ f16 Bs[64 * 48];
  const int tid = threadIdx.x;
  const int lane = tid & 63;
  const int w = tid >> 6;
  const int b0 = blockIdx.x * 32;
  const int j0 = blockIdx.y * 64;

  // stage A once: post-reset h rows b0..b0+31 (f16)
  {
    const int row = tid >> 3;        // 0..31
    const int kp = (tid & 7) * 64;   // 0..448
    const int rs = resets[t * BB + b0 + row];
    const f16x8* src = (const f16x8*)(h16i + (size_t)(b0 + row) * HH + kp);
    f16x8* dst = (f16x8*)&As[row * 520 + kp];
    if (rs) {
      f16x8 z = {};
      for (int u = 0; u < 8; ++u) dst[u] = z;
    } else {
      for (int u = 0; u < 8; ++u) dst[u] = src[u];
    }
  }

  const int mt = (w & 1) * 16;     // wave m offset (0 or 16)
  const int nq = (w >> 1) * 2;     // wave n-tile pair index
  const int fr = lane & 15;
  const int fq8 = (lane >> 4) * 8;
  const int sn = tid >> 2;         // 0..63
  const int skp = (tid & 3) * 8;

  f32x4 acc[3][2] = {};

  for (int g = 0; g < 3; ++g) {
    const f16* Wg = WhT + (size_t)(g * HH + j0) * HH;
    for (int kb = 0; kb < 16; ++kb) {
      const int k0 = kb * 32;
      *(f16x8*)&Bs[sn * 48 + skp] =
          *(const f16x8*)(Wg + (size_t)sn * HH + k0 + skp);
      __syncthreads();
      f16x8 a = *(const f16x8*)&As[(mt + fr) * 520 + k0 + fq8];
      f16x8 bf0 = *(const f16x8*)&Bs[((nq) * 16 + fr) * 48 + fq8];
      f16x8 bf1 = *(const f16x8*)&Bs[((nq + 1) * 16 + fr) * 48 + fq8];
      acc[g][0] = __builtin_amdgcn_mfma_f32_16x16x32_f16(a, bf0, acc[g][0], 0, 0, 0);
      acc[g][1] = __builtin_amdgcn_mfma_f32_16x16x32_f16(a, bf1, acc[g][1], 0, 0, 0);
      __syncthreads();
    }
  }

  // fused gate math + update
  const int trow = (lane >> 4) * 4;
  for (int ni = 0; ni < 2; ++ni) {
    const int j = j0 + (nq + ni) * 16 + fr;
    const float bh = bhn[j];
    for (int r = 0; r < 4; ++r) {
      const int b = b0 + mt + trow + r;
      const size_t gbase = (size_t)(t * BB + b) * H3 + j;
      const float gr = (float)gi[gbase];
      const float gz = (float)gi[gbase + 512];
      const float gn = (float)gi[gbase + 1024];
      const float rr = 1.f / (1.f + __expf(-(gr + acc[0][ni][r])));
      const float zz = 1.f / (1.f + __expf(-(gz + acc[1][ni][r])));
      const float nn = tanhf(gn + rr * (acc[2][ni][r] + bh));
      float hp = resets[t * BB + b] ? 0.f : h32i[(size_t)b * HH + j];
      const float hnew = (1.f - zz) * nn + zz * hp;
      out[(size_t)(t * BB + b) * HH + j] = hnew;
      h32o[(size_t)b * HH + j] = hnew;
      h16o[(size_t)b * HH + j] = (f16)hnew;
    }
  }
}

// ---------------------------------------------------------------------------
extern "C" void kernel_launch(void* const* d_in, const int* in_sizes, int n_in,
                              void* d_out, int out_size, void* d_ws, size_t ws_size,
                              hipStream_t stream) {
  const float* x = (const float*)d_in[0];
  const int* resets = (const int*)d_in[1];
  const float* Wi = (const float*)d_in[2];
  const float* bi = (const float*)d_in[3];
  const float* Wh = (const float*)d_in[4];
  const float* bhn = (const float*)d_in[5];
  const float* h0 = (const float*)d_in[6];
  float* out = (float*)d_out;

  // workspace layout (~205.3 MB)
  char* ws = (char*)d_ws;
  size_t off = 0;
  f16* gi = (f16*)(ws + off);   off += (size_t)TBR * H3 * sizeof(f16);   // 201.3 MB
  f16* WiT = (f16*)(ws + off);  off += (size_t)HH * H3 * sizeof(f16);    // 1.5 MB
  f16* WhT = (f16*)(ws + off);  off += (size_t)HH * H3 * sizeof(f16);    // 1.5 MB
  float* h32a = (float*)(ws + off); off += (size_t)BB * HH * sizeof(float);
  float* h32b = (float*)(ws + off); off += (size_t)BB * HH * sizeof(float);
  f16* h16a = (f16*)(ws + off); off += (size_t)BB * HH * sizeof(f16);
  f16* h16b = (f16*)(ws + off); off += (size_t)BB * HH * sizeof(f16);
  (void)ws_size; (void)in_sizes; (void)n_in; (void)out_size;

  k_prep<<<dim3((HH * H3) / 256), 256, 0, stream>>>(Wi, Wh, h0, WiT, WhT, h32a, h16a);
  k_gemm_gi<<<dim3(TBR / 64, H3 / 64), 256, 0, stream>>>(x, WiT, bi, gi);

  float* h32[2] = {h32a, h32b};
  f16* h16[2] = {h16a, h16b};
  for (int t = 0; t < TT; ++t) {
    const int i = t & 1, o = i ^ 1;
    k_step<<<dim3(BB / 32, HH / 64), 256, 0, stream>>>(
        t, resets, WhT, gi, bhn, out, h32[i], h32[o], h16[i], h16[o]);
  }
}